// Round 7
// baseline (392.856 us; speedup 1.0000x reference)
//
#include <hip/hip_runtime.h>
#include <hip/hip_bf16.h>
#include <stdint.h>

// MoE FFN, top-1 routing. x:[4,2048,1024] f32, 8 experts, 1024->4096->1024.
// R7: 256x128 BK=64 depth-3 pipelined MFMA GEMM (3x48KB LDS buffers,
//     WAIT_VM(6) counted, stage T+2 during T), 256-row m-tiles.

#define D_MODEL 1024
#define D_FF    4096
#define NEXP    8
#define NTOK    8192
#define MAXT256 40

typedef __attribute__((ext_vector_type(8))) short bf16x8;
typedef __attribute__((ext_vector_type(8))) unsigned short u16x8;
typedef __attribute__((ext_vector_type(4))) unsigned short u16x4;
typedef __attribute__((ext_vector_type(4))) float f32x4;

// ---- workspace layout (bytes) ----
#define OFF_META 0u
#define OFF_TOPI 4096u
#define OFF_PERM 36864u
#define OFF_POS  69632u
#define OFF_XG   131072u                     // 10496*1024*2 rows padded
#define OFF_H    21626880u                   // 10496*4096*2
#define OFF_W1T  107610112u                  // 8*4096*1024*2
#define OFF_W2T  174718976u                  // 8*1024*4096*2 (end ~242 MB)

__device__ __forceinline__ unsigned short f2bf(float f) {
  unsigned int u = __builtin_bit_cast(unsigned int, f);
  unsigned int r = (u + 0x7FFFu + ((u >> 16) & 1u)) >> 16;
  return (unsigned short)r;
}

typedef const __attribute__((address_space(1))) unsigned int* gas_u32;
typedef __attribute__((address_space(3))) unsigned int* las_u32;

__device__ __forceinline__ void gload16(const void* g, void* l) {
  __builtin_amdgcn_global_load_lds((gas_u32)g, (las_u32)l, 16, 0, 0);
}

__device__ __forceinline__ int xcd_swz(int orig, int nwg) {
  int q = nwg >> 3, r = nwg & 7;
  int xcd = orig & 7, lid = orig >> 3;
  return (xcd < r ? xcd * (q + 1) : r * (q + 1) + (xcd - r) * q) + lid;
}

// ---------------- gating: one wave per token, fp64 accumulate ----------------
__global__ __launch_bounds__(256) void gate_kernel(const float* __restrict__ x,
    const float* __restrict__ gw, const float* __restrict__ gb,
    const float* __restrict__ eb, int* __restrict__ topi) {
  int wid = threadIdx.x >> 6, lane = threadIdx.x & 63;
  int t = blockIdx.x * 4 + wid;
  const float* xr = x + (size_t)t * D_MODEL;
  double p[NEXP];
#pragma unroll
  for (int e = 0; e < NEXP; ++e) p[e] = 0.0;
#pragma unroll
  for (int j = 0; j < D_MODEL / 64; ++j) {
    int c = lane + j * 64;
    double xv = (double)xr[c];
#pragma unroll
    for (int e = 0; e < NEXP; ++e) p[e] += xv * (double)gw[e * D_MODEL + c];
  }
#pragma unroll
  for (int e = 0; e < NEXP; ++e) {
    for (int off = 32; off; off >>= 1) p[e] += __shfl_xor(p[e], off, 64);
  }
  if (lane == 0) {
    double best = -1e300; int bi = 0;
#pragma unroll
    for (int e = 0; e < NEXP; ++e) {
      double v = p[e] + (double)gb[e] + (double)eb[e];
      if (v > best) { best = v; bi = e; }
    }
    topi[t] = bi;
  }
}

// ---- rank kernel: 1 block, 1024 threads. counts/offsets/tilemap/pos/perm ----
__global__ __launch_bounds__(1024) void rank_kernel(const int* __restrict__ topi,
    int* __restrict__ meta, int* __restrict__ pos, int* __restrict__ perm) {
  __shared__ int hist[NEXP][1024];
  __shared__ int offs_s[NEXP + 1];
  int tid = threadIdx.x;
  int te[8], loc[NEXP], run[NEXP];
#pragma unroll
  for (int e = 0; e < NEXP; ++e) loc[e] = 0;
#pragma unroll
  for (int j = 0; j < 8; ++j) {
    te[j] = topi[tid * 8 + j];
#pragma unroll
    for (int e = 0; e < NEXP; ++e) loc[e] += (te[j] == e) ? 1 : 0;
  }
#pragma unroll
  for (int e = 0; e < NEXP; ++e) { run[e] = loc[e]; hist[e][tid] = run[e]; }
  __syncthreads();
  for (int s = 1; s < 1024; s <<= 1) {
    int v[NEXP];
#pragma unroll
    for (int e = 0; e < NEXP; ++e) v[e] = (tid >= s) ? hist[e][tid - s] : 0;
    __syncthreads();
#pragma unroll
    for (int e = 0; e < NEXP; ++e) { run[e] += v[e]; hist[e][tid] = run[e]; }
    __syncthreads();
  }
  if (tid == 1023) {
    int o = 0, nt = 0;
    for (int e = 0; e < NEXP; ++e) {
      offs_s[e] = o;
      meta[e] = run[e];
      meta[8 + e] = o;
      o += run[e];
    }
    offs_s[NEXP] = o; meta[16] = o;
    for (int e = 0; e < NEXP; ++e) {
      int ntile = (run[e] + 255) >> 8;        // 256-row m-tiles
      for (int j = 0; j < ntile; ++j) { meta[32 + nt] = e; meta[112 + nt] = j; ++nt; }
    }
    meta[25] = nt;
  }
  __syncthreads();
  int base[NEXP];
#pragma unroll
  for (int e = 0; e < NEXP; ++e) base[e] = offs_s[e] + run[e] - loc[e];
#pragma unroll
  for (int j = 0; j < 8; ++j) {
    int tok = tid * 8 + j, pj = 0;
#pragma unroll
    for (int e = 0; e < NEXP; ++e) {
      if (te[j] == e) pj = base[e];
      base[e] += (te[j] == e) ? 1 : 0;
    }
    pos[tok] = pj;
    perm[pj] = tok;
  }
}

// -------- scatter tokens into per-expert contiguous rows, f32 -> bf16 --------
__global__ __launch_bounds__(256) void scatter_kernel(const float* __restrict__ x,
    const int* __restrict__ pos, unsigned short* __restrict__ xg) {
  int t = blockIdx.x;
  int p = pos[t];
  const float* xr = x + (size_t)t * D_MODEL;
  unsigned short* orow = xg + (size_t)p * D_MODEL;
  int c = threadIdx.x * 4;
  f32x4 v = *(const f32x4*)(xr + c);
  u16x4 u;
#pragma unroll
  for (int j = 0; j < 4; ++j) u[j] = f2bf(v[j]);
  *(u16x4*)(orow + c) = u;
}

// ---- weight convert+transpose: [E][R][C] f32 -> [E][C][R] bf16 ----
__global__ __launch_bounds__(256) void transconv2(const float* __restrict__ in,
    unsigned short* __restrict__ out, int R, int C) {
  __shared__ float tile[64][65];
  int e = blockIdx.z;
  const float* src = in + (size_t)e * R * C;
  unsigned short* dst = out + (size_t)e * R * C;
  int c0 = blockIdx.x * 64, r0 = blockIdx.y * 64;
  int tid = threadIdx.x;
  int rr = tid >> 4, cc4 = (tid & 15) * 4;
#pragma unroll
  for (int i = 0; i < 4; ++i) {
    f32x4 v = *(const f32x4*)(src + (size_t)(r0 + rr + i * 16) * C + c0 + cc4);
#pragma unroll
    for (int j = 0; j < 4; ++j) tile[rr + i * 16][cc4 + j] = v[j];
  }
  __syncthreads();
  int cc = tid >> 3, rr8 = (tid & 7) * 8;
#pragma unroll
  for (int i = 0; i < 2; ++i) {
    int c = cc + i * 32;
    u16x8 u;
#pragma unroll
    for (int j = 0; j < 8; ++j) u[j] = f2bf(tile[rr8 + j][c]);
    *(u16x8*)(dst + (size_t)(c0 + c) * R + r0 + rr8) = u;
  }
}

// ----- depth-3 pipelined 256x128 grouped GEMM, 8 waves (2Mx4N), BK=64 ------
// LDS = 3 bufs x 48KB { A: 256rows x 128B | B: 128rows x 128B }.
// Tile T reads buf[T%3]; stages tile T+2 into buf[(T+2)%3] (read-free since
// the T-1/T boundary barrier). 6 loads/thread/tile; WAIT_VM(6) at tile end
// -> T+1 fully landed, T+2's 6 in flight (never drains; T4).
// Swizzle both sides: byte ^= ((row&7)<<4).
#define SBAR() { __builtin_amdgcn_sched_barrier(0); __builtin_amdgcn_s_barrier(); __builtin_amdgcn_sched_barrier(0); }
#define WAIT_VM(N) { asm volatile("s_waitcnt vmcnt(" #N ")" ::: "memory"); __builtin_amdgcn_sched_barrier(0); }

template<int KDIM, int NDIM, bool IS_FFN1>
__global__ __launch_bounds__(512, 1) void gemm3p(
    const unsigned short* __restrict__ A, const unsigned short* __restrict__ Bt,
    const float* __restrict__ bias, const int* __restrict__ meta,
    const int* __restrict__ perm, unsigned short* __restrict__ H,
    float* __restrict__ Out) {
  constexpr int NT = KDIM / 64;
  constexpr int SK = KDIM * 2;
  constexpr int NP = NDIM / 128;
  int ntiles = meta[25];
  int nwg = ntiles * NP;
  int orig = blockIdx.x;
  if (orig >= nwg) return;
  int wid = xcd_swz(orig, nwg);
  int nb = wid / ntiles, t = wid % ntiles;   // n-outer, m-inner (expert-seq)

  int e = meta[32 + t];
  int lm = meta[112 + t];
  int off = meta[8 + e];
  int rowsValid = meta[9 + e] - off - lm * 256;
  int m0 = off + lm * 256;

  __shared__ char lds[147456];               // 3 x 49152

  int tid = threadIdx.x;
  int lane = tid & 63, wv = tid >> 6;
  int waveM = wv >> 2, waveN = wv & 3;       // 2M x 4N; wave tile 128m x 32n
  int lr = lane & 15, lg = lane >> 4;

  const char* aBase = (const char*)(A + (size_t)m0 * KDIM);
  const char* bBase = (const char*)(Bt + ((size_t)e * NDIM + nb * 128) * KDIM);

#define ST_A(D, KT) { \
    char* _d = lds + (D) * 49152; \
    _Pragma("unroll") for (int _j = 0; _j < 4; ++_j) { \
      int _o = tid * 16 + _j * 8192; \
      int _lw = _o >> 7; \
      int _co = (_o & 127) ^ ((_lw & 7) << 4); \
      gload16(aBase + (size_t)_lw * SK + (KT) * 128 + _co, _d + _o); } }
#define ST_B(D, KT) { \
    char* _d = lds + (D) * 49152 + 32768; \
    _Pragma("unroll") for (int _j = 0; _j < 2; ++_j) { \
      int _o = tid * 16 + _j * 8192; \
      int _lw = _o >> 7; \
      int _co = (_o & 127) ^ ((_lw & 7) << 4); \
      gload16(bBase + (size_t)_lw * SK + (KT) * 128 + _co, _d + _o); } }

  bf16x8 a[4][2], b[2][2];
#define LD_A(D, MH) { \
    const char* _b = lds + (D) * 49152; \
    _Pragma("unroll") for (int mfi = 0; mfi < 4; ++mfi) \
    _Pragma("unroll") for (int ks = 0; ks < 2; ++ks) { \
      int _o = (waveM * 128 + (MH) * 64 + mfi * 16 + lr) * 128 + ks * 64 + lg * 16; \
      _o ^= ((_o >> 7) & 7) << 4; \
      a[mfi][ks] = *(const bf16x8*)(_b + _o); } }
#define LD_B(D) { \
    const char* _b = lds + (D) * 49152 + 32768; \
    _Pragma("unroll") for (int nfi = 0; nfi < 2; ++nfi) \
    _Pragma("unroll") for (int ks = 0; ks < 2; ++ks) { \
      int _o = (waveN * 32 + nfi * 16 + lr) * 128 + ks * 64 + lg * 16; \
      _o ^= ((_o >> 7) & 7) << 4; \
      b[nfi][ks] = *(const bf16x8*)(_b + _o); } }

  f32x4 acc[8][2];
#pragma unroll
  for (int i = 0; i < 8; ++i)
#pragma unroll
    for (int j = 0; j < 2; ++j) acc[i][j] = (f32x4){0.f, 0.f, 0.f, 0.f};

#define MM(MH) { \
    __builtin_amdgcn_s_setprio(1); \
    _Pragma("unroll") for (int mfi = 0; mfi < 4; ++mfi) \
    _Pragma("unroll") for (int nfi = 0; nfi < 2; ++nfi) \
    _Pragma("unroll") for (int ks = 0; ks < 2; ++ks) \
      acc[(MH) * 4 + mfi][nfi] = __builtin_amdgcn_mfma_f32_16x16x32_bf16( \
          a[mfi][ks], b[nfi][ks], acc[(MH) * 4 + mfi][nfi], 0, 0, 0); \
    __builtin_amdgcn_s_setprio(0); }

  // prologue: stage tile0 -> buf0, tile1 -> buf1 (12 loads); wait 6 = tile0 in.
  ST_A(0, 0); ST_B(0, 0);
  ST_A(1, 1); ST_B(1, 1);
  WAIT_VM(6); SBAR();

  int cur = 0, nx = 2;
  for (int T = 0; T < NT; ++T) {
    int kt2 = T + 2 < NT ? T + 2 : NT - 1;
    // p1: read A-half0 + B of cur; stage A(T+2)
    LD_A(cur, 0); LD_B(cur);
    ST_A(nx, kt2);
    SBAR();
    MM(0);
    SBAR();
    // p2: read A-half1; stage B(T+2); counted wait -> T+1 landed
    LD_A(cur, 1);
    ST_B(nx, kt2);
    SBAR();
    MM(1);
    WAIT_VM(6);
    SBAR();
    cur = cur + 1 == 3 ? 0 : cur + 1;
    nx = nx + 1 == 3 ? 0 : nx + 1;
  }
  asm volatile("s_waitcnt vmcnt(0)" ::: "memory");

  // epilogue: C/D map col=lane&15, row=(lane>>4)*4+reg
  int cb = nb * 128 + waveN * 32;
#pragma unroll
  for (int mf = 0; mf < 8; ++mf) {
#pragma unroll
    for (int rg = 0; rg < 4; ++rg) {
      int rowt = waveM * 128 + mf * 16 + lg * 4 + rg;
      if (rowt >= rowsValid) continue;
      if (IS_FFN1) {
        size_t ro = (size_t)(m0 + rowt) * NDIM;
#pragma unroll
        for (int nf = 0; nf < 2; ++nf) {
          int col = cb + nf * 16 + lr;
          float v = acc[mf][nf][rg] + bias[e * NDIM + col];
          H[ro + col] = f2bf(fmaxf(v, 0.f));
        }
      } else {
        int tok = perm[m0 + rowt];
        size_t ro = (size_t)tok * NDIM;
#pragma unroll
        for (int nf = 0; nf < 2; ++nf) {
          int col = cb + nf * 16 + lr;
          Out[ro + col] = acc[mf][nf][rg] + bias[e * NDIM + col];
        }
      }
    }
  }
#undef ST_A
#undef ST_B
#undef LD_A
#undef LD_B
#undef MM
}

extern "C" void kernel_launch(void* const* d_in, const int* in_sizes, int n_in,
                              void* d_out, int out_size, void* d_ws, size_t ws_size,
                              hipStream_t stream) {
  const float* x  = (const float*)d_in[0];
  const float* gw = (const float*)d_in[1];
  const float* gb = (const float*)d_in[2];
  const float* eb = (const float*)d_in[3];
  const float* w1 = (const float*)d_in[4];
  const float* b1 = (const float*)d_in[5];
  const float* w2 = (const float*)d_in[6];
  const float* b2 = (const float*)d_in[7];
  float* out = (float*)d_out;

  char* ws = (char*)d_ws;
  int* meta = (int*)(ws + OFF_META);
  int* topi = (int*)(ws + OFF_TOPI);
  int* perm = (int*)(ws + OFF_PERM);
  int* pos  = (int*)(ws + OFF_POS);
  unsigned short* xg  = (unsigned short*)(ws + OFF_XG);
  unsigned short* h   = (unsigned short*)(ws + OFF_H);
  unsigned short* w1t = (unsigned short*)(ws + OFF_W1T);
  unsigned short* w2t = (unsigned short*)(ws + OFF_W2T);

  hipLaunchKernelGGL(gate_kernel, dim3(NTOK / 4), dim3(256), 0, stream, x, gw, gb, eb, topi);
  hipLaunchKernelGGL(rank_kernel, dim3(1), dim3(1024), 0, stream, topi, meta, pos, perm);
  hipLaunchKernelGGL(scatter_kernel, dim3(NTOK), dim3(256), 0, stream, x, pos, xg);
  hipLaunchKernelGGL(transconv2, dim3(D_FF / 64, D_MODEL / 64, NEXP), dim3(256), 0, stream,
                     w1, w1t, D_MODEL, D_FF);
  hipLaunchKernelGGL(transconv2, dim3(D_MODEL / 64, D_FF / 64, NEXP), dim3(256), 0, stream,
                     w2, w2t, D_FF, D_MODEL);
  hipLaunchKernelGGL((gemm3p<D_MODEL, D_FF, true>), dim3(MAXT256 * (D_FF / 128)), dim3(512), 0, stream,
                     xg, w1t, b1, meta, perm, h, nullptr);
  hipLaunchKernelGGL((gemm3p<D_FF, D_MODEL, false>), dim3(MAXT256 * (D_MODEL / 128)), dim3(512), 0, stream,
                     h, w2t, b2, meta, perm, nullptr, out);
}

// Round 8
// 333.939 us; speedup vs baseline: 1.1764x; 1.1764x over previous
//
#include <hip/hip_runtime.h>
#include <hip/hip_bf16.h>
#include <stdint.h>

// MoE FFN, top-1 routing. x:[4,2048,1024] f32, 8 experts, 1024->4096->1024.
// R8: R5 routing stack + R4 256x256 8-wave gemm8 with m201-style stage map
//     (one half-tile per phase, WAIT_VM(6), 3 half-tiles always in flight).

#define D_MODEL 1024
#define D_FF    4096
#define NEXP    8
#define NTOK    8192
#define MAXT256 40

typedef __attribute__((ext_vector_type(8))) short bf16x8;
typedef __attribute__((ext_vector_type(8))) unsigned short u16x8;
typedef __attribute__((ext_vector_type(4))) unsigned short u16x4;
typedef __attribute__((ext_vector_type(4))) float f32x4;

// ---- workspace layout (bytes) ----
#define OFF_META 0u
#define OFF_TOPI 4096u
#define OFF_PERM 36864u
#define OFF_POS  69632u
#define OFF_XG   131072u                     // 8448*1024*2
#define OFF_H    17432576u                   // 8448*4096*2
#define OFF_W1T  86638592u                   // 8*4096*1024*2
#define OFF_W2T  153747456u                  // 8*1024*4096*2

__device__ __forceinline__ unsigned short f2bf(float f) {
  unsigned int u = __builtin_bit_cast(unsigned int, f);
  unsigned int r = (u + 0x7FFFu + ((u >> 16) & 1u)) >> 16;
  return (unsigned short)r;
}

typedef const __attribute__((address_space(1))) unsigned int* gas_u32;
typedef __attribute__((address_space(3))) unsigned int* las_u32;

__device__ __forceinline__ void gload16(const void* g, void* l) {
  __builtin_amdgcn_global_load_lds((gas_u32)g, (las_u32)l, 16, 0, 0);
}

__device__ __forceinline__ int xcd_swz(int orig, int nwg) {
  int q = nwg >> 3, r = nwg & 7;
  int xcd = orig & 7, lid = orig >> 3;
  return (xcd < r ? xcd * (q + 1) : r * (q + 1) + (xcd - r) * q) + lid;
}

// ---------------- gating: one wave per token, fp64 accumulate ----------------
__global__ __launch_bounds__(256) void gate_kernel(const float* __restrict__ x,
    const float* __restrict__ gw, const float* __restrict__ gb,
    const float* __restrict__ eb, int* __restrict__ topi) {
  int wid = threadIdx.x >> 6, lane = threadIdx.x & 63;
  int t = blockIdx.x * 4 + wid;
  const float* xr = x + (size_t)t * D_MODEL;
  double p[NEXP];
#pragma unroll
  for (int e = 0; e < NEXP; ++e) p[e] = 0.0;
#pragma unroll
  for (int j = 0; j < D_MODEL / 64; ++j) {
    int c = lane + j * 64;
    double xv = (double)xr[c];
#pragma unroll
    for (int e = 0; e < NEXP; ++e) p[e] += xv * (double)gw[e * D_MODEL + c];
  }
#pragma unroll
  for (int e = 0; e < NEXP; ++e) {
    for (int off = 32; off; off >>= 1) p[e] += __shfl_xor(p[e], off, 64);
  }
  if (lane == 0) {
    double best = -1e300; int bi = 0;
#pragma unroll
    for (int e = 0; e < NEXP; ++e) {
      double v = p[e] + (double)gb[e] + (double)eb[e];
      if (v > best) { best = v; bi = e; }
    }
    topi[t] = bi;
  }
}

// ---- rank kernel: 1 block, 1024 threads. counts/offsets/tilemap/pos/perm ----
__global__ __launch_bounds__(1024) void rank_kernel(const int* __restrict__ topi,
    int* __restrict__ meta, int* __restrict__ pos, int* __restrict__ perm) {
  __shared__ int hist[NEXP][1024];
  __shared__ int offs_s[NEXP + 1];
  int tid = threadIdx.x;
  int te[8], loc[NEXP], run[NEXP];
#pragma unroll
  for (int e = 0; e < NEXP; ++e) loc[e] = 0;
#pragma unroll
  for (int j = 0; j < 8; ++j) {
    te[j] = topi[tid * 8 + j];
#pragma unroll
    for (int e = 0; e < NEXP; ++e) loc[e] += (te[j] == e) ? 1 : 0;
  }
#pragma unroll
  for (int e = 0; e < NEXP; ++e) { run[e] = loc[e]; hist[e][tid] = run[e]; }
  __syncthreads();
  for (int s = 1; s < 1024; s <<= 1) {
    int v[NEXP];
#pragma unroll
    for (int e = 0; e < NEXP; ++e) v[e] = (tid >= s) ? hist[e][tid - s] : 0;
    __syncthreads();
#pragma unroll
    for (int e = 0; e < NEXP; ++e) { run[e] += v[e]; hist[e][tid] = run[e]; }
    __syncthreads();
  }
  if (tid == 1023) {
    int o = 0, nt = 0;
    for (int e = 0; e < NEXP; ++e) {
      offs_s[e] = o;
      meta[e] = run[e];
      meta[8 + e] = o;
      o += run[e];
    }
    offs_s[NEXP] = o; meta[16] = o;
    for (int e = 0; e < NEXP; ++e) {
      int ntile = (run[e] + 255) >> 8;        // 256-row m-tiles
      for (int j = 0; j < ntile; ++j) { meta[32 + nt] = e; meta[112 + nt] = j; ++nt; }
    }
    meta[25] = nt;
  }
  __syncthreads();
  int base[NEXP];
#pragma unroll
  for (int e = 0; e < NEXP; ++e) base[e] = offs_s[e] + run[e] - loc[e];
#pragma unroll
  for (int j = 0; j < 8; ++j) {
    int tok = tid * 8 + j, pj = 0;
#pragma unroll
    for (int e = 0; e < NEXP; ++e) {
      if (te[j] == e) pj = base[e];
      base[e] += (te[j] == e) ? 1 : 0;
    }
    pos[tok] = pj;
    perm[pj] = tok;
  }
}

// -------- scatter tokens into per-expert contiguous rows, f32 -> bf16 --------
__global__ __launch_bounds__(256) void scatter_kernel(const float* __restrict__ x,
    const int* __restrict__ pos, unsigned short* __restrict__ xg) {
  int t = blockIdx.x;
  int p = pos[t];
  const float* xr = x + (size_t)t * D_MODEL;
  unsigned short* orow = xg + (size_t)p * D_MODEL;
  int c = threadIdx.x * 4;
  f32x4 v = *(const f32x4*)(xr + c);
  u16x4 u;
#pragma unroll
  for (int j = 0; j < 4; ++j) u[j] = f2bf(v[j]);
  *(u16x4*)(orow + c) = u;
}

// ---- weight convert+transpose: [E][R][C] f32 -> [E][C][R] bf16 ----
__global__ __launch_bounds__(256) void transconv2(const float* __restrict__ in,
    unsigned short* __restrict__ out, int R, int C) {
  __shared__ float tile[64][65];
  int e = blockIdx.z;
  const float* src = in + (size_t)e * R * C;
  unsigned short* dst = out + (size_t)e * R * C;
  int c0 = blockIdx.x * 64, r0 = blockIdx.y * 64;
  int tid = threadIdx.x;
  int rr = tid >> 4, cc4 = (tid & 15) * 4;
#pragma unroll
  for (int i = 0; i < 4; ++i) {
    f32x4 v = *(const f32x4*)(src + (size_t)(r0 + rr + i * 16) * C + c0 + cc4);
#pragma unroll
    for (int j = 0; j < 4; ++j) tile[rr + i * 16][cc4 + j] = v[j];
  }
  __syncthreads();
  int cc = tid >> 3, rr8 = (tid & 7) * 8;
#pragma unroll
  for (int i = 0; i < 2; ++i) {
    int c = cc + i * 32;
    u16x8 u;
#pragma unroll
    for (int j = 0; j < 8; ++j) u[j] = f2bf(tile[rr8 + j][c]);
    *(u16x8*)(dst + (size_t)(c0 + c) * R + r0 + rr8) = u;
  }
}

// ---------------- 8-phase 256x256 grouped GEMM (bf16 MFMA) ------------------
// A [rows][KDIM] bf16, Bt [E][NDIM][KDIM] bf16. 8 waves 2Mx4N, BK=64.
// LDS 128KB: 2 dbuf x { A:[mh0|mh1] 16KB each, B:[nh0|nh1] 16KB each }.
// Reads: p1:{A0,B0} p2:{B1} p3:{A1} p4:{B0}.
// Stage map (tile T): p1: B0(T+1)->dn; p2: A0(T+2)->cur; p3: B1(T+2);
// p4: A1(T+2). WAIT_VM(6) at p4 completes exactly through B0(T+1) ->
// tile T+1 fully resident; 3 half-tiles always in flight (never drains).
// Swizzle both sides: byte ^= ((row&7)<<4).
#define SBAR() { __builtin_amdgcn_sched_barrier(0); __builtin_amdgcn_s_barrier(); __builtin_amdgcn_sched_barrier(0); }
#define WAIT_VM(N) { asm volatile("s_waitcnt vmcnt(" #N ")" ::: "memory"); __builtin_amdgcn_sched_barrier(0); }

template<int KDIM, int NDIM, bool IS_FFN1>
__global__ __launch_bounds__(512, 1) void gemm8(
    const unsigned short* __restrict__ A, const unsigned short* __restrict__ Bt,
    const float* __restrict__ bias, const int* __restrict__ meta,
    const int* __restrict__ perm, unsigned short* __restrict__ H,
    float* __restrict__ Out) {
  constexpr int NT = KDIM / 64;
  constexpr int SK = KDIM * 2;
  const int NP = NDIM / 256;
  int ntiles = meta[25];
  int nwg = ntiles * NP;
  int orig = blockIdx.x;
  if (orig >= nwg) return;
  int wid = xcd_swz(orig, nwg);
  int t = wid % ntiles, nb = wid / ntiles;   // n-outer, m-inner

  int e = meta[32 + t];
  int lm = meta[112 + t];
  int off = meta[8 + e];
  int rowsValid = meta[9 + e] - off - lm * 256;
  int m0 = off + lm * 256;

  __shared__ char lds[131072];

  int tid = threadIdx.x;
  int lane = tid & 63, wv = tid >> 6;
  int waveM = wv >> 2, waveN = wv & 3;       // 2M x 4N
  int lr = lane & 15, lg = lane >> 4;

  const char* aBase = (const char*)(A + (size_t)m0 * KDIM);
  const char* bBase = (const char*)(Bt + ((size_t)e * NDIM + nb * 256) * KDIM);

  const int o0 = tid * 16, o1 = o0 + 8192;
  const int lw0 = o0 >> 7, lw1 = o1 >> 7;
  const int co0 = (o0 & 127) ^ ((lw0 & 7) << 4);
  const int co1 = (o1 & 127) ^ ((lw1 & 7) << 4);
  const int mA0 = (lw0 >> 6) * 128 + (lw0 & 63), mA1 = (lw1 >> 6) * 128 + (lw1 & 63);
  const int nB0 = (lw0 >> 5) * 64 + (lw0 & 31), nB1 = (lw1 >> 5) * 64 + (lw1 & 31);

#define ST_A(D, R, KT) { \
    char* _d = lds + (D) * 65536 + (R) * 16384; \
    gload16(aBase + (size_t)(mA0 + (R) * 64) * SK + (KT) * 128 + co0, _d + o0); \
    gload16(aBase + (size_t)(mA1 + (R) * 64) * SK + (KT) * 128 + co1, _d + o1); }
#define ST_B(D, R, KT) { \
    char* _d = lds + (D) * 65536 + 32768 + (R) * 16384; \
    gload16(bBase + (size_t)(nB0 + (R) * 32) * SK + (KT) * 128 + co0, _d + o0); \
    gload16(bBase + (size_t)(nB1 + (R) * 32) * SK + (KT) * 128 + co1, _d + o1); }

  bf16x8 a[4][2], b[2][2];
#define LD_A(D, MH) { \
    const char* _b = lds + (D) * 65536 + (MH) * 16384; \
    _Pragma("unroll") for (int mfi = 0; mfi < 4; ++mfi) \
    _Pragma("unroll") for (int ks = 0; ks < 2; ++ks) { \
      int _o = (waveM * 64 + mfi * 16 + lr) * 128 + ks * 64 + lg * 16; \
      _o ^= ((_o >> 7) & 7) << 4; \
      a[mfi][ks] = *(const bf16x8*)(_b + _o); } }
#define LD_B(D, NH) { \
    const char* _b = lds + (D) * 65536 + 32768 + (NH) * 16384; \
    _Pragma("unroll") for (int nfi = 0; nfi < 2; ++nfi) \
    _Pragma("unroll") for (int ks = 0; ks < 2; ++ks) { \
      int _o = (waveN * 32 + nfi * 16 + lr) * 128 + ks * 64 + lg * 16; \
      _o ^= ((_o >> 7) & 7) << 4; \
      b[nfi][ks] = *(const bf16x8*)(_b + _o); } }

  f32x4 acc[8][4];
#pragma unroll
  for (int i = 0; i < 8; ++i)
#pragma unroll
    for (int j = 0; j < 4; ++j) acc[i][j] = (f32x4){0.f, 0.f, 0.f, 0.f};

#define MM(MH, NH) { \
    __builtin_amdgcn_s_setprio(1); \
    _Pragma("unroll") for (int mfi = 0; mfi < 4; ++mfi) \
    _Pragma("unroll") for (int nfi = 0; nfi < 2; ++nfi) \
    _Pragma("unroll") for (int ks = 0; ks < 2; ++ks) \
      acc[(MH) * 4 + mfi][(NH) * 2 + nfi] = __builtin_amdgcn_mfma_f32_16x16x32_bf16( \
          a[mfi][ks], b[nfi][ks], acc[(MH) * 4 + mfi][(NH) * 2 + nfi], 0, 0, 0); \
    __builtin_amdgcn_s_setprio(0); }

  // prologue: tile0 all 4 halves + tile1 {A0,B1,A1}; wait(6) -> tile0 landed,
  // {A0,B1,A1}(1) in flight (steady state).
  {
    int k1 = NT > 1 ? 1 : 0;
    ST_A(0, 0, 0); ST_B(0, 1, 0); ST_A(0, 1, 0); ST_B(0, 0, 0);
    ST_A(1, 0, k1); ST_B(1, 1, k1); ST_A(1, 1, k1);
  }
  WAIT_VM(6); SBAR();

  for (int T = 0; T < NT; ++T) {
    int d = T & 1, dn = d ^ 1;
    int tp1 = T + 1 < NT ? T + 1 : T;
    int tp2 = T + 2 < NT ? T + 2 : T;
    // p1 (mh0,nh0): stage B0(T+1) -> dn (free since T-1 p4)
    LD_A(d, 0); LD_B(d, 0);
    ST_B(dn, 0, tp1);
    SBAR();
    MM(0, 0);
    SBAR();
    // p2 (mh0,nh1): stage A0(T+2) -> cur (A0 last read p1)
    LD_B(d, 1);
    ST_A(d, 0, tp2);
    SBAR();
    MM(0, 1);
    SBAR();
    // p3 (mh1,nh1): stage B1(T+2) -> cur (B1 last read p2)
    LD_A(d, 1);
    ST_B(d, 1, tp2);
    SBAR();
    MM(1, 1);
    SBAR();
    // p4 (mh1,nh0): stage A1(T+2) -> cur (A1 last read p3); counted wait
    LD_B(d, 0);
    ST_A(d, 1, tp2);
    SBAR();
    MM(1, 0);
    WAIT_VM(6);
    SBAR();
  }
  asm volatile("s_waitcnt vmcnt(0)" ::: "memory");

  // epilogue: C/D map col=lane&15, row=(lane>>4)*4+reg
  int cb = nb * 256 + waveN * 64;
#pragma unroll
  for (int mf = 0; mf < 8; ++mf) {
#pragma unroll
    for (int rg = 0; rg < 4; ++rg) {
      int rowt = waveM * 128 + mf * 16 + lg * 4 + rg;
      if (rowt >= rowsValid) continue;
      if (IS_FFN1) {
        size_t ro = (size_t)(m0 + rowt) * NDIM;
#pragma unroll
        for (int nf = 0; nf < 4; ++nf) {
          int col = cb + nf * 16 + lr;
          float v = acc[mf][nf][rg] + bias[e * NDIM + col];
          H[ro + col] = f2bf(fmaxf(v, 0.f));
        }
      } else {
        int tok = perm[m0 + rowt];
        size_t ro = (size_t)tok * NDIM;
#pragma unroll
        for (int nf = 0; nf < 4; ++nf) {
          int col = cb + nf * 16 + lr;
          Out[ro + col] = acc[mf][nf][rg] + bias[e * NDIM + col];
        }
      }
    }
  }
#undef ST_A
#undef ST_B
#undef LD_A
#undef LD_B
#undef MM
}

extern "C" void kernel_launch(void* const* d_in, const int* in_sizes, int n_in,
                              void* d_out, int out_size, void* d_ws, size_t ws_size,
                              hipStream_t stream) {
  const float* x  = (const float*)d_in[0];
  const float* gw = (const float*)d_in[1];
  const float* gb = (const float*)d_in[2];
  const float* eb = (const float*)d_in[3];
  const float* w1 = (const float*)d_in[4];
  const float* b1 = (const float*)d_in[5];
  const float* w2 = (const float*)d_in[6];
  const float* b2 = (const float*)d_in[7];
  float* out = (float*)d_out;

  char* ws = (char*)d_ws;
  int* meta = (int*)(ws + OFF_META);
  int* topi = (int*)(ws + OFF_TOPI);
  int* perm = (int*)(ws + OFF_PERM);
  int* pos  = (int*)(ws + OFF_POS);
  unsigned short* xg  = (unsigned short*)(ws + OFF_XG);
  unsigned short* h   = (unsigned short*)(ws + OFF_H);
  unsigned short* w1t = (unsigned short*)(ws + OFF_W1T);
  unsigned short* w2t = (unsigned short*)(ws + OFF_W2T);

  hipLaunchKernelGGL(gate_kernel, dim3(NTOK / 4), dim3(256), 0, stream, x, gw, gb, eb, topi);
  hipLaunchKernelGGL(rank_kernel, dim3(1), dim3(1024), 0, stream, topi, meta, pos, perm);
  hipLaunchKernelGGL(scatter_kernel, dim3(NTOK), dim3(256), 0, stream, x, pos, xg);
  hipLaunchKernelGGL(transconv2, dim3(D_FF / 64, D_MODEL / 64, NEXP), dim3(256), 0, stream,
                     w1, w1t, D_MODEL, D_FF);
  hipLaunchKernelGGL(transconv2, dim3(D_MODEL / 64, D_FF / 64, NEXP), dim3(256), 0, stream,
                     w2, w2t, D_FF, D_MODEL);
  hipLaunchKernelGGL((gemm8<D_MODEL, D_FF, true>), dim3(MAXT256 * (D_FF / 256)), dim3(512), 0, stream,
                     xg, w1t, b1, meta, perm, h, nullptr);
  hipLaunchKernelGGL((gemm8<D_FF, D_MODEL, false>), dim3(MAXT256 * (D_MODEL / 256)), dim3(512), 0, stream,
                     h, w2t, b2, meta, perm, nullptr, out);
}

// Round 9
// 330.602 us; speedup vs baseline: 1.1883x; 1.0101x over previous
//
#include <hip/hip_runtime.h>
#include <hip/hip_bf16.h>
#include <stdint.h>

// MoE FFN, top-1 routing. x:[4,2048,1024] f32, 8 experts, 1024->4096->1024.
// R9: R8 + B0 register retention (each LDS half read exactly once per K-tile),
//     vectorized gate, merged transconv launch.

#define D_MODEL 1024
#define D_FF    4096
#define NEXP    8
#define NTOK    8192
#define MAXT256 40

typedef __attribute__((ext_vector_type(8))) short bf16x8;
typedef __attribute__((ext_vector_type(8))) unsigned short u16x8;
typedef __attribute__((ext_vector_type(4))) unsigned short u16x4;
typedef __attribute__((ext_vector_type(4))) float f32x4;

// ---- workspace layout (bytes) ----
#define OFF_META 0u
#define OFF_TOPI 4096u
#define OFF_PERM 36864u
#define OFF_POS  69632u
#define OFF_XG   131072u                     // 8448*1024*2
#define OFF_H    17432576u                   // 8448*4096*2
#define OFF_W1T  86638592u                   // 8*4096*1024*2
#define OFF_W2T  153747456u                  // 8*1024*4096*2

__device__ __forceinline__ unsigned short f2bf(float f) {
  unsigned int u = __builtin_bit_cast(unsigned int, f);
  unsigned int r = (u + 0x7FFFu + ((u >> 16) & 1u)) >> 16;
  return (unsigned short)r;
}

typedef const __attribute__((address_space(1))) unsigned int* gas_u32;
typedef __attribute__((address_space(3))) unsigned int* las_u32;

__device__ __forceinline__ void gload16(const void* g, void* l) {
  __builtin_amdgcn_global_load_lds((gas_u32)g, (las_u32)l, 16, 0, 0);
}

__device__ __forceinline__ int xcd_swz(int orig, int nwg) {
  int q = nwg >> 3, r = nwg & 7;
  int xcd = orig & 7, lid = orig >> 3;
  return (xcd < r ? xcd * (q + 1) : r * (q + 1) + (xcd - r) * q) + lid;
}

// ---------------- gating: one wave per token, fp64 accumulate ----------------
__global__ __launch_bounds__(256) void gate_kernel(const float* __restrict__ x,
    const float* __restrict__ gw, const float* __restrict__ gb,
    const float* __restrict__ eb, int* __restrict__ topi) {
  int wid = threadIdx.x >> 6, lane = threadIdx.x & 63;
  int t = blockIdx.x * 4 + wid;
  const float* xr = x + (size_t)t * D_MODEL;
  double p[NEXP];
#pragma unroll
  for (int e = 0; e < NEXP; ++e) p[e] = 0.0;
#pragma unroll
  for (int j = 0; j < 4; ++j) {
    int c = (lane + j * 64) * 4;
    f32x4 xv = *(const f32x4*)(xr + c);
#pragma unroll
    for (int e = 0; e < NEXP; ++e) {
      f32x4 gv = *(const f32x4*)(gw + e * D_MODEL + c);
#pragma unroll
      for (int q = 0; q < 4; ++q) p[e] += (double)xv[q] * (double)gv[q];
    }
  }
#pragma unroll
  for (int e = 0; e < NEXP; ++e) {
    for (int off = 32; off; off >>= 1) p[e] += __shfl_xor(p[e], off, 64);
  }
  if (lane == 0) {
    double best = -1e300; int bi = 0;
#pragma unroll
    for (int e = 0; e < NEXP; ++e) {
      double v = p[e] + (double)gb[e] + (double)eb[e];
      if (v > best) { best = v; bi = e; }
    }
    topi[t] = bi;
  }
}

// ---- rank kernel: 1 block, 1024 threads. counts/offsets/tilemap/pos/perm ----
__global__ __launch_bounds__(1024) void rank_kernel(const int* __restrict__ topi,
    int* __restrict__ meta, int* __restrict__ pos, int* __restrict__ perm) {
  __shared__ int hist[NEXP][1024];
  __shared__ int offs_s[NEXP + 1];
  int tid = threadIdx.x;
  int te[8], loc[NEXP], run[NEXP];
#pragma unroll
  for (int e = 0; e < NEXP; ++e) loc[e] = 0;
#pragma unroll
  for (int j = 0; j < 8; ++j) {
    te[j] = topi[tid * 8 + j];
#pragma unroll
    for (int e = 0; e < NEXP; ++e) loc[e] += (te[j] == e) ? 1 : 0;
  }
#pragma unroll
  for (int e = 0; e < NEXP; ++e) { run[e] = loc[e]; hist[e][tid] = run[e]; }
  __syncthreads();
  for (int s = 1; s < 1024; s <<= 1) {
    int v[NEXP];
#pragma unroll
    for (int e = 0; e < NEXP; ++e) v[e] = (tid >= s) ? hist[e][tid - s] : 0;
    __syncthreads();
#pragma unroll
    for (int e = 0; e < NEXP; ++e) { run[e] += v[e]; hist[e][tid] = run[e]; }
    __syncthreads();
  }
  if (tid == 1023) {
    int o = 0, nt = 0;
    for (int e = 0; e < NEXP; ++e) {
      offs_s[e] = o;
      meta[e] = run[e];
      meta[8 + e] = o;
      o += run[e];
    }
    offs_s[NEXP] = o; meta[16] = o;
    for (int e = 0; e < NEXP; ++e) {
      int ntile = (run[e] + 255) >> 8;        // 256-row m-tiles
      for (int j = 0; j < ntile; ++j) { meta[32 + nt] = e; meta[112 + nt] = j; ++nt; }
    }
    meta[25] = nt;
  }
  __syncthreads();
  int base[NEXP];
#pragma unroll
  for (int e = 0; e < NEXP; ++e) base[e] = offs_s[e] + run[e] - loc[e];
#pragma unroll
  for (int j = 0; j < 8; ++j) {
    int tok = tid * 8 + j, pj = 0;
#pragma unroll
    for (int e = 0; e < NEXP; ++e) {
      if (te[j] == e) pj = base[e];
      base[e] += (te[j] == e) ? 1 : 0;
    }
    pos[tok] = pj;
    perm[pj] = tok;
  }
}

// -------- scatter tokens into per-expert contiguous rows, f32 -> bf16 --------
__global__ __launch_bounds__(256) void scatter_kernel(const float* __restrict__ x,
    const int* __restrict__ pos, unsigned short* __restrict__ xg) {
  int t = blockIdx.x;
  int p = pos[t];
  const float* xr = x + (size_t)t * D_MODEL;
  unsigned short* orow = xg + (size_t)p * D_MODEL;
  int c = threadIdx.x * 4;
  f32x4 v = *(const f32x4*)(xr + c);
  u16x4 u;
#pragma unroll
  for (int j = 0; j < 4; ++j) u[j] = f2bf(v[j]);
  *(u16x4*)(orow + c) = u;
}

// ---- merged weight convert+transpose: both w1 and w2 in one launch ----
// [E][R][C] f32 -> [E][C][R] bf16, 64x64 tiles. id<8192: w1 (R=1024,C=4096);
// else: w2 (R=4096,C=1024). 1024 tiles per expert in both cases.
__global__ __launch_bounds__(256) void transconv_all(
    const float* __restrict__ w1, unsigned short* __restrict__ w1t,
    const float* __restrict__ w2, unsigned short* __restrict__ w2t) {
  __shared__ float tile[64][65];
  int id = blockIdx.x;
  const float* src; unsigned short* dst; int R, C, c0, r0;
  if (id < 8192) {
    int e = id >> 10, rem = id & 1023;       // 64 c-tiles x 16 r-tiles
    R = 1024; C = 4096;
    c0 = (rem & 63) * 64; r0 = (rem >> 6) * 64;
    src = w1 + (size_t)e * R * C; dst = w1t + (size_t)e * R * C;
  } else {
    int e = (id - 8192) >> 10, rem = (id - 8192) & 1023;  // 16 x 64
    R = 4096; C = 1024;
    c0 = (rem & 15) * 64; r0 = (rem >> 4) * 64;
    src = w2 + (size_t)e * R * C; dst = w2t + (size_t)e * R * C;
  }
  int tid = threadIdx.x;
  int rr = tid >> 4, cc4 = (tid & 15) * 4;
#pragma unroll
  for (int i = 0; i < 4; ++i) {
    f32x4 v = *(const f32x4*)(src + (size_t)(r0 + rr + i * 16) * C + c0 + cc4);
#pragma unroll
    for (int j = 0; j < 4; ++j) tile[rr + i * 16][cc4 + j] = v[j];
  }
  __syncthreads();
  int cc = tid >> 3, rr8 = (tid & 7) * 8;
#pragma unroll
  for (int i = 0; i < 2; ++i) {
    int c = cc + i * 32;
    u16x8 u;
#pragma unroll
    for (int j = 0; j < 8; ++j) u[j] = f2bf(tile[rr8 + j][c]);
    *(u16x8*)(dst + (size_t)(c0 + c) * R + r0 + rr8) = u;
  }
}

// ---------------- 8-phase 256x256 grouped GEMM (bf16 MFMA) ------------------
// A [rows][KDIM] bf16, Bt [E][NDIM][KDIM] bf16. 8 waves 2Mx4N, BK=64.
// LDS 128KB: 2 dbuf x { A:[mh0|mh1] 16KB, B:[nh0|nh1] 16KB }.
// R9: each LDS half read EXACTLY ONCE per K-tile (B0 kept in b0 regs for p4).
// Reads: p1:{A0->a,B0->b0} p2:{B1->b1} p3:{A1->a} p4:{} .
// Stage map (tile T): p1: B0(T+1)->dn; p2: A0(T+2)->cur; p3: B1(T+2);
// p4: A1(T+2). WAIT_VM(6) at p4 -> tile T+1 fully resident; {A0,B1,A1}(T+2)
// in flight (never drains). Swizzle both sides: byte ^= ((row&7)<<4).
#define SBAR() { __builtin_amdgcn_sched_barrier(0); __builtin_amdgcn_s_barrier(); __builtin_amdgcn_sched_barrier(0); }
#define WAIT_VM(N) { asm volatile("s_waitcnt vmcnt(" #N ")" ::: "memory"); __builtin_amdgcn_sched_barrier(0); }

template<int KDIM, int NDIM, bool IS_FFN1>
__global__ __launch_bounds__(512, 1) void gemm8(
    const unsigned short* __restrict__ A, const unsigned short* __restrict__ Bt,
    const float* __restrict__ bias, const int* __restrict__ meta,
    const int* __restrict__ perm, unsigned short* __restrict__ H,
    float* __restrict__ Out) {
  constexpr int NT = KDIM / 64;
  constexpr int SK = KDIM * 2;
  const int NP = NDIM / 256;
  int ntiles = meta[25];
  int nwg = ntiles * NP;
  int orig = blockIdx.x;
  if (orig >= nwg) return;
  int wid = xcd_swz(orig, nwg);
  int t = wid % ntiles, nb = wid / ntiles;   // n-outer, m-inner

  int e = meta[32 + t];
  int lm = meta[112 + t];
  int off = meta[8 + e];
  int rowsValid = meta[9 + e] - off - lm * 256;
  int m0 = off + lm * 256;

  __shared__ char lds[131072];

  int tid = threadIdx.x;
  int lane = tid & 63, wv = tid >> 6;
  int waveM = wv >> 2, waveN = wv & 3;       // 2M x 4N
  int lr = lane & 15, lg = lane >> 4;

  const char* aBase = (const char*)(A + (size_t)m0 * KDIM);
  const char* bBase = (const char*)(Bt + ((size_t)e * NDIM + nb * 256) * KDIM);

  const int o0 = tid * 16, o1 = o0 + 8192;
  const int lw0 = o0 >> 7, lw1 = o1 >> 7;
  const int co0 = (o0 & 127) ^ ((lw0 & 7) << 4);
  const int co1 = (o1 & 127) ^ ((lw1 & 7) << 4);
  const int mA0 = (lw0 >> 6) * 128 + (lw0 & 63), mA1 = (lw1 >> 6) * 128 + (lw1 & 63);
  const int nB0 = (lw0 >> 5) * 64 + (lw0 & 31), nB1 = (lw1 >> 5) * 64 + (lw1 & 31);

#define ST_A(D, R, KT) { \
    char* _d = lds + (D) * 65536 + (R) * 16384; \
    gload16(aBase + (size_t)(mA0 + (R) * 64) * SK + (KT) * 128 + co0, _d + o0); \
    gload16(aBase + (size_t)(mA1 + (R) * 64) * SK + (KT) * 128 + co1, _d + o1); }
#define ST_B(D, R, KT) { \
    char* _d = lds + (D) * 65536 + 32768 + (R) * 16384; \
    gload16(bBase + (size_t)(nB0 + (R) * 32) * SK + (KT) * 128 + co0, _d + o0); \
    gload16(bBase + (size_t)(nB1 + (R) * 32) * SK + (KT) * 128 + co1, _d + o1); }

  bf16x8 a[4][2], b0[2][2], b1[2][2];
#define LD_A(D, MH) { \
    const char* _b = lds + (D) * 65536 + (MH) * 16384; \
    _Pragma("unroll") for (int mfi = 0; mfi < 4; ++mfi) \
    _Pragma("unroll") for (int ks = 0; ks < 2; ++ks) { \
      int _o = (waveM * 64 + mfi * 16 + lr) * 128 + ks * 64 + lg * 16; \
      _o ^= ((_o >> 7) & 7) << 4; \
      a[mfi][ks] = *(const bf16x8*)(_b + _o); } }
#define LD_B(D, NH, BV) { \
    const char* _b = lds + (D) * 65536 + 32768 + (NH) * 16384; \
    _Pragma("unroll") for (int nfi = 0; nfi < 2; ++nfi) \
    _Pragma("unroll") for (int ks = 0; ks < 2; ++ks) { \
      int _o = (waveN * 32 + nfi * 16 + lr) * 128 + ks * 64 + lg * 16; \
      _o ^= ((_o >> 7) & 7) << 4; \
      BV[nfi][ks] = *(const bf16x8*)(_b + _o); } }

  f32x4 acc[8][4];
#pragma unroll
  for (int i = 0; i < 8; ++i)
#pragma unroll
    for (int j = 0; j < 4; ++j) acc[i][j] = (f32x4){0.f, 0.f, 0.f, 0.f};

#define MM(MH, NH, BV) { \
    __builtin_amdgcn_s_setprio(1); \
    _Pragma("unroll") for (int mfi = 0; mfi < 4; ++mfi) \
    _Pragma("unroll") for (int nfi = 0; nfi < 2; ++nfi) \
    _Pragma("unroll") for (int ks = 0; ks < 2; ++ks) \
      acc[(MH) * 4 + mfi][(NH) * 2 + nfi] = __builtin_amdgcn_mfma_f32_16x16x32_bf16( \
          a[mfi][ks], BV[nfi][ks], acc[(MH) * 4 + mfi][(NH) * 2 + nfi], 0, 0, 0); \
    __builtin_amdgcn_s_setprio(0); }

  // prologue: tile0 all 4 halves + tile1 {A0,B1,A1}; wait(6) -> tile0 landed,
  // {A0,B1,A1}(1) in flight (steady state).
  {
    int k1 = NT > 1 ? 1 : 0;
    ST_A(0, 0, 0); ST_B(0, 1, 0); ST_A(0, 1, 0); ST_B(0, 0, 0);
    ST_A(1, 0, k1); ST_B(1, 1, k1); ST_A(1, 1, k1);
  }
  WAIT_VM(6); SBAR();

  for (int T = 0; T < NT; ++T) {
    int d = T & 1, dn = d ^ 1;
    int tp1 = T + 1 < NT ? T + 1 : T;
    int tp2 = T + 2 < NT ? T + 2 : T;
    // p1 (mh0,nh0): stage B0(T+1) -> dn (free since T-1 p4)
    LD_A(d, 0); LD_B(d, 0, b0);
    ST_B(dn, 0, tp1);
    SBAR();
    MM(0, 0, b0);
    SBAR();
    // p2 (mh0,nh1): stage A0(T+2) -> cur (A0 last read p1)
    LD_B(d, 1, b1);
    ST_A(d, 0, tp2);
    SBAR();
    MM(0, 1, b1);
    SBAR();
    // p3 (mh1,nh1): stage B1(T+2) -> cur (B1 last read p2)
    LD_A(d, 1);
    ST_B(d, 1, tp2);
    SBAR();
    MM(1, 1, b1);
    SBAR();
    // p4 (mh1,nh0): no LDS reads (b0 retained); stage A1(T+2); counted wait
    ST_A(d, 1, tp2);
    SBAR();
    MM(1, 0, b0);
    WAIT_VM(6);
    SBAR();
  }
  asm volatile("s_waitcnt vmcnt(0)" ::: "memory");

  // epilogue: C/D map col=lane&15, row=(lane>>4)*4+reg
  int cb = nb * 256 + waveN * 64;
#pragma unroll
  for (int mf = 0; mf < 8; ++mf) {
#pragma unroll
    for (int rg = 0; rg < 4; ++rg) {
      int rowt = waveM * 128 + mf * 16 + lg * 4 + rg;
      if (rowt >= rowsValid) continue;
      if (IS_FFN1) {
        size_t ro = (size_t)(m0 + rowt) * NDIM;
#pragma unroll
        for (int nf = 0; nf < 4; ++nf) {
          int col = cb + nf * 16 + lr;
          float v = acc[mf][nf][rg] + bias[e * NDIM + col];
          H[ro + col] = f2bf(fmaxf(v, 0.f));
        }
      } else {
        int tok = perm[m0 + rowt];
        size_t ro = (size_t)tok * NDIM;
#pragma unroll
        for (int nf = 0; nf < 4; ++nf) {
          int col = cb + nf * 16 + lr;
          Out[ro + col] = acc[mf][nf][rg] + bias[e * NDIM + col];
        }
      }
    }
  }
#undef ST_A
#undef ST_B
#undef LD_A
#undef LD_B
#undef MM
}

extern "C" void kernel_launch(void* const* d_in, const int* in_sizes, int n_in,
                              void* d_out, int out_size, void* d_ws, size_t ws_size,
                              hipStream_t stream) {
  const float* x  = (const float*)d_in[0];
  const float* gw = (const float*)d_in[1];
  const float* gb = (const float*)d_in[2];
  const float* eb = (const float*)d_in[3];
  const float* w1 = (const float*)d_in[4];
  const float* b1 = (const float*)d_in[5];
  const float* w2 = (const float*)d_in[6];
  const float* b2 = (const float*)d_in[7];
  float* out = (float*)d_out;

  char* ws = (char*)d_ws;
  int* meta = (int*)(ws + OFF_META);
  int* topi = (int*)(ws + OFF_TOPI);
  int* perm = (int*)(ws + OFF_PERM);
  int* pos  = (int*)(ws + OFF_POS);
  unsigned short* xg  = (unsigned short*)(ws + OFF_XG);
  unsigned short* h   = (unsigned short*)(ws + OFF_H);
  unsigned short* w1t = (unsigned short*)(ws + OFF_W1T);
  unsigned short* w2t = (unsigned short*)(ws + OFF_W2T);

  hipLaunchKernelGGL(gate_kernel, dim3(NTOK / 4), dim3(256), 0, stream, x, gw, gb, eb, topi);
  hipLaunchKernelGGL(rank_kernel, dim3(1), dim3(1024), 0, stream, topi, meta, pos, perm);
  hipLaunchKernelGGL(scatter_kernel, dim3(NTOK), dim3(256), 0, stream, x, pos, xg);
  hipLaunchKernelGGL(transconv_all, dim3(16384), dim3(256), 0, stream, w1, w1t, w2, w2t);
  hipLaunchKernelGGL((gemm8<D_MODEL, D_FF, true>), dim3(MAXT256 * (D_FF / 256)), dim3(512), 0, stream,
                     xg, w1t, b1, meta, perm, h, nullptr);
  hipLaunchKernelGGL((gemm8<D_FF, D_MODEL, false>), dim3(MAXT256 * (D_MODEL / 256)), dim3(512), 0, stream,
                     h, w2t, b2, meta, perm, nullptr, out);
}